// Round 5
// baseline (549.255 us; speedup 1.0000x reference)
//
#include <hip/hip_runtime.h>
#include <hip/hip_bf16.h>
#include <math.h>

typedef __hip_bfloat16 bf16;
typedef __attribute__((ext_vector_type(8))) short short8v;
typedef __attribute__((ext_vector_type(4))) float float4v;

__device__ __forceinline__ float b2f(bf16 v) { return __bfloat162float(v); }
__device__ __forceinline__ float bs2f(unsigned short s) {
    unsigned u = ((unsigned)s) << 16;
    float f; __builtin_memcpy(&f, &u, 4); return f;
}
__device__ __forceinline__ short f2bs(float v) {
    bf16 b = __float2bfloat16(v);
    short s; __builtin_memcpy(&s, &b, 2); return s;
}
__device__ __forceinline__ float lrelu(float v) { return v > 0.f ? v : 0.2f * v; }
__device__ __forceinline__ float ldf(const void* p, size_t i, int bf) {
    return bf ? b2f(((const bf16*)p)[i]) : ((const float*)p)[i];
}
__device__ __forceinline__ int ld_src(const int* ei, int e, int E, int f64, int N) {
    int v = f64 ? (int)(((const long long*)ei)[e]) : ei[e];
    if ((unsigned)v >= (unsigned)N) v = 0;
    return v;
}
__device__ __forceinline__ int ld_dst(const int* ei, int e, int E, int f64, int N) {
    int v = f64 ? (int)(((const long long*)ei)[(size_t)E + e]) : ei[(size_t)E + e];
    if ((unsigned)v >= (unsigned)N) v = 0;
    return v;
}

// ---------------------------------------------------------------------------
// K0: dtype detection. flags[0]=int64 edge index, flags[1]=bf16 floats.
// ---------------------------------------------------------------------------
__global__ void k_detect(const int* __restrict__ ei, const unsigned* __restrict__ xw,
                         int* __restrict__ flags)
{
    __shared__ int s_or[256];
    __shared__ int s_cnt[256];
    int t = threadIdx.x;
    int any = 0, cnt = 0;
    for (int i = t; i < 4096; i += 256) {
        any |= ei[2 * i + 1];
        unsigned e = (xw[i] >> 7) & 0xFFu;
        cnt += (e >= 100u && e <= 134u) ? 1 : 0;
    }
    s_or[t] = any; s_cnt[t] = cnt;
    __syncthreads();
    for (int s = 128; s > 0; s >>= 1) {
        if (t < s) { s_or[t] |= s_or[t + s]; s_cnt[t] += s_cnt[t + s]; }
        __syncthreads();
    }
    if (t == 0) {
        flags[0] = (s_or[0] == 0) ? 1 : 0;
        flags[1] = (s_cnt[0] > 2048) ? 1 : 0;
    }
}

__global__ void k_zero(int* __restrict__ p, int n)
{
    int i = blockIdx.x * blockDim.x + threadIdx.x;
    if (i < n) p[i] = 0;
}

// ---------------------------------------------------------------------------
// K1: h1 = x @ W1 via MFMA 16x16x32 bf16. Block = 256 thr (4 waves), 64 rows.
// W1 staged transposed [n][k] in LDS (padded), x-tile staged [m][k].
// A-frag: A[m=lane&15][k=quad*8+j]; B-frag: B[k=quad*8+j][n=lane&15];
// C: col=lane&15, row=quad*4+reg.
// ---------------------------------------------------------------------------
#define GP 136  // padded LDS row in elements (136*2=272 B, 16B-aligned, 2-way banks)

__global__ void __launch_bounds__(256)
k_gemm1_mfma(const void* __restrict__ x, const void* __restrict__ W1,
             const int* __restrict__ flags, bf16* __restrict__ h1b, int N)
{
    __shared__ short w1t[128 * GP];  // 34,816 B
    __shared__ short xs[64 * GP];    // 17,408 B
    int bf = flags[1];
    int t = threadIdx.x;
    int m0 = blockIdx.x * 64;

    for (int idx = t; idx < 16384; idx += 256) {
        int k = idx >> 7, nn = idx & 127;
        w1t[nn * GP + k] = bf ? ((const short*)W1)[idx] : f2bs(((const float*)W1)[idx]);
    }
    for (int idx = t; idx < 8192; idx += 256) {
        int m = idx >> 7, k = idx & 127;
        int gm = m0 + m;
        float v = (gm < N) ? ldf(x, (size_t)gm * 128 + k, bf) : 0.f;
        xs[m * GP + k] = f2bs(v);
    }
    __syncthreads();

    int wv = t >> 6, l = t & 63, lq = l >> 4, lr = l & 15;

    short8v afr[4];
#pragma unroll
    for (int kk = 0; kk < 4; ++kk)
        afr[kk] = *(const short8v*)&xs[(wv * 16 + lr) * GP + kk * 32 + lq * 8];

    float4v acc[8];
#pragma unroll
    for (int ct = 0; ct < 8; ++ct) acc[ct] = (float4v){0.f, 0.f, 0.f, 0.f};

#pragma unroll
    for (int kk = 0; kk < 4; ++kk) {
        short8v a = afr[kk];
#pragma unroll
        for (int ct = 0; ct < 8; ++ct) {
            short8v b = *(const short8v*)&w1t[(ct * 16 + lr) * GP + kk * 32 + lq * 8];
            acc[ct] = __builtin_amdgcn_mfma_f32_16x16x32_bf16(a, b, acc[ct], 0, 0, 0);
        }
    }

#pragma unroll
    for (int ct = 0; ct < 8; ++ct) {
#pragma unroll
        for (int r = 0; r < 4; ++r) {
            int row = m0 + wv * 16 + lq * 4 + r;
            if (row < N)
                h1b[(size_t)row * 128 + ct * 16 + lr] = __float2bfloat16(acc[ct][r]);
        }
    }
}

// ---------------------------------------------------------------------------
// K2: a_s/a_d from h1b. One wave per node (lane owns 2 cols via ushort2).
// ---------------------------------------------------------------------------
__global__ void k_asd(const bf16* __restrict__ h1b, const void* __restrict__ att_src,
                      const void* __restrict__ att_dst, const int* __restrict__ flags,
                      float* __restrict__ a_s, float* __restrict__ a_d, int N)
{
    int bf = flags[1];
    int gid = blockIdx.x * blockDim.x + threadIdx.x;
    int n = gid >> 6, l = gid & 63;
    if (n >= N) return;
    ushort2 u = *(const ushort2*)((const unsigned short*)h1b + (size_t)n * 128 + 2 * l);
    float v0 = bs2f(u.x), v1 = bs2f(u.y);
    float ps = v0 * ldf(att_src, 2 * l, bf) + v1 * ldf(att_src, 2 * l + 1, bf);
    float pd = v0 * ldf(att_dst, 2 * l, bf) + v1 * ldf(att_dst, 2 * l + 1, bf);
    for (int m = 1; m < 16; m <<= 1) {
        ps += __shfl_xor(ps, m, 64);
        pd += __shfl_xor(pd, m, 64);
    }
    if ((l & 15) == 0) {
        a_s[(size_t)n * 4 + (l >> 4)] = ps;
        a_d[(size_t)n * 4 + (l >> 4)] = pd;
    }
}

// ---------------------------------------------------------------------------
// CSR-by-dst build
// ---------------------------------------------------------------------------
__global__ void k_count(const int* __restrict__ ei, const int* __restrict__ flags,
                        int* __restrict__ counts, int E, int N)
{
    int e = blockIdx.x * blockDim.x + threadIdx.x;
    if (e < E) atomicAdd(&counts[ld_dst(ei, e, E, flags[0], N)], 1);
}

__global__ void k_bsum(const int* __restrict__ counts, int* __restrict__ bsums, int N)
{
    __shared__ int sdata[512];
    int i = blockIdx.x * 512 + threadIdx.x;
    sdata[threadIdx.x] = (i < N) ? counts[i] : 0;
    __syncthreads();
    for (int s = 256; s > 0; s >>= 1) {
        if (threadIdx.x < s) sdata[threadIdx.x] += sdata[threadIdx.x + s];
        __syncthreads();
    }
    if (threadIdx.x == 0) bsums[blockIdx.x] = sdata[0];
}

__global__ void k_scan_bsums(int* bsums, int nb)
{
    __shared__ int sh[512];
    int t = threadIdx.x;
    int v = (t < nb) ? bsums[t] : 0;
    sh[t] = v;
    __syncthreads();
    for (int s = 1; s < 512; s <<= 1) {
        int add = (t >= s) ? sh[t - s] : 0;
        __syncthreads();
        sh[t] += add;
        __syncthreads();
    }
    if (t < nb) bsums[t] = sh[t] - v;
}

__global__ void k_offsets(const int* __restrict__ counts, const int* __restrict__ bsums,
                          int* __restrict__ offsets, int* __restrict__ cursor, int N, int E)
{
    __shared__ int sdata[512];
    int i = blockIdx.x * 512 + threadIdx.x;
    int v = (i < N) ? counts[i] : 0;
    sdata[threadIdx.x] = v;
    __syncthreads();
    for (int s = 1; s < 512; s <<= 1) {
        int add = (threadIdx.x >= (unsigned)s) ? sdata[threadIdx.x - s] : 0;
        __syncthreads();
        sdata[threadIdx.x] += add;
        __syncthreads();
    }
    if (i < N) {
        int excl = sdata[threadIdx.x] - v + bsums[blockIdx.x];
        offsets[i] = excl;
        cursor[i] = excl;
    }
    if (blockIdx.x == 0 && threadIdx.x == 0) offsets[N] = E;
}

__global__ void k_scatter(const int* __restrict__ ei, const int* __restrict__ flags,
                          int* __restrict__ cursor, int* __restrict__ adj, int E, int N)
{
    int e = blockIdx.x * blockDim.x + threadIdx.x;
    if (e < E) {
        int f = flags[0];
        int d = ld_dst(ei, e, E, f, N);
        int pos = atomicAdd(&cursor[d], 1);
        adj[pos] = ld_src(ei, e, E, f, N);
    }
}

// ---------------------------------------------------------------------------
// K7: layer-1 softmax-aggregate (no max shift), fused +b1, ReLU, W2 proj.
// Block = 128 thr (2 waves) per node. Waves split the edge list; within a
// wave, lanes 0-31 process edge A, 32-63 edge B; each lane owns 4 columns
// via one ushort4 load. Cross-wave/sub partials combine through LDS.
// ---------------------------------------------------------------------------
__global__ void __launch_bounds__(128)
k_agg1(const bf16* __restrict__ h1b, const float* __restrict__ a_s,
       const float* __restrict__ a_d, const int* __restrict__ offsets,
       const int* __restrict__ adj, const void* __restrict__ b1,
       const void* __restrict__ W2, const int* __restrict__ flags,
       float* __restrict__ h2, int N)
{
    int bf = flags[1];
    int n = blockIdx.x, t = threadIdx.x;
    int w = t >> 6, l = t & 63, sub = l >> 5, j = l & 31;
    int hh = j >> 3;  // head of cols 4j..4j+3

    __shared__ float sad[4], sself[4], sden[4];
    __shared__ float swt[128 * 5];
    __shared__ int   sadj[128];
    __shared__ float facc[2][128];
    __shared__ float swred[2][4];
    __shared__ float w2sum[2];

    int beg = offsets[n], deg = offsets[n + 1] - beg;
    if (t < 4) {
        float adv = a_d[(size_t)n * 4 + t];
        sad[t] = adv;
        sself[t] = __expf(lrelu(a_s[(size_t)n * 4 + t] + adv));
    }
    __syncthreads();
    float ad0 = sad[0], ad1 = sad[1], ad2 = sad[2], ad3 = sad[3];

    float a0 = 0.f, a1 = 0.f, a2 = 0.f, a3 = 0.f;      // col partials
    float dd0 = 0.f, dd1 = 0.f, dd2 = 0.f, dd3 = 0.f;  // denom partials
    const float4* as4 = (const float4*)a_s;
    const unsigned short* h1u = (const unsigned short*)h1b;

    for (int base = 0; base < deg; base += 128) {
        int chunk = min(128, deg - base);
        __syncthreads();
        if (t < chunk) {
            int s = adj[beg + base + t];
            sadj[t] = s;
            float4 av = as4[s];
            float w0 = __expf(lrelu(av.x + ad0));
            float w1 = __expf(lrelu(av.y + ad1));
            float w2v = __expf(lrelu(av.z + ad2));
            float w3 = __expf(lrelu(av.w + ad3));
            swt[t * 5 + 0] = w0; swt[t * 5 + 1] = w1;
            swt[t * 5 + 2] = w2v; swt[t * 5 + 3] = w3;
            dd0 += w0; dd1 += w1; dd2 += w2v; dd3 += w3;
        }
        __syncthreads();
        // wave w handles edges {4k+2w, 4k+2w+1}; sub picks one of the pair
        for (int k4 = 4 * 0 + 2 * w; k4 < chunk; k4 += 4) {
            int e = k4 + sub;
            if (e < chunk) {
                int s = sadj[e];
                float wt = swt[e * 5 + hh];
                ushort4 u = *(const ushort4*)(h1u + ((size_t)s << 7) + 4 * j);
                a0 += wt * bs2f(u.x);
                a1 += wt * bs2f(u.y);
                a2 += wt * bs2f(u.z);
                a3 += wt * bs2f(u.w);
            }
        }
    }
    // denom: reduce over all 128 threads
    for (int m = 1; m < 64; m <<= 1) {
        dd0 += __shfl_xor(dd0, m, 64);
        dd1 += __shfl_xor(dd1, m, 64);
        dd2 += __shfl_xor(dd2, m, 64);
        dd3 += __shfl_xor(dd3, m, 64);
    }
    if (l == 0) { swred[w][0] = dd0; swred[w][1] = dd1; swred[w][2] = dd2; swred[w][3] = dd3; }
    // col partials: combine sub halves within wave, then stash per wave
    a0 += __shfl_xor(a0, 32, 64);
    a1 += __shfl_xor(a1, 32, 64);
    a2 += __shfl_xor(a2, 32, 64);
    a3 += __shfl_xor(a3, 32, 64);
    if (sub == 0) {
        facc[w][4 * j + 0] = a0; facc[w][4 * j + 1] = a1;
        facc[w][4 * j + 2] = a2; facc[w][4 * j + 3] = a3;
    }
    __syncthreads();
    if (t < 4) sden[t] = swred[0][t] + swred[1][t] + sself[t];
    __syncthreads();

    float selfv = sself[t >> 5] * b2f(h1b[((size_t)n << 7) + t]);
    float o = (facc[0][t] + facc[1][t] + selfv) / (sden[t >> 5] + 1e-16f) + ldf(b1, t, bf);
    o = fmaxf(o, 0.f);  // inter-layer ReLU

    float p = o * ldf(W2, t, bf);
    for (int m = 1; m < 64; m <<= 1) p += __shfl_xor(p, m, 64);
    if (l == 0) w2sum[w] = p;
    __syncthreads();
    if (t == 0) h2[n] = w2sum[0] + w2sum[1];
}

// ---------------------------------------------------------------------------
// K8: layer-2 scalar softmax-aggregate, single pass. 16 lanes per node.
// ---------------------------------------------------------------------------
__global__ void k_agg2(const float* __restrict__ h2, const int* __restrict__ offsets,
                       const int* __restrict__ adj, const void* __restrict__ att_src2,
                       const void* __restrict__ att_dst2, const void* __restrict__ bias2,
                       const int* __restrict__ flags, void* __restrict__ out, int N)
{
    int bf = flags[1];
    int g = (blockIdx.x * blockDim.x + threadIdx.x) >> 4;
    int lane = threadIdx.x & 15;
    if (g >= N) return;
    int n = g;
    float as2 = ldf(att_src2, 0, bf), ad2 = ldf(att_dst2, 0, bf);
    int beg = offsets[n], end = offsets[n + 1], deg = end - beg;
    float hn = h2[n];
    float dterm = hn * ad2;

    float acc = 0.f, den = 0.f;
    if (lane == 0) {
        float ex = __expf(lrelu(hn * as2 + dterm));
        acc = ex * hn; den = ex;
    }
    for (int i = lane; i < deg; i += 16) {
        int s = adj[beg + i];
        float hs = h2[s];
        float ex = __expf(lrelu(hs * as2 + dterm));
        acc += ex * hs; den += ex;
    }
    for (int m = 1; m < 16; m <<= 1) {
        acc += __shfl_xor(acc, m, 64);
        den += __shfl_xor(den, m, 64);
    }
    if (lane == 0) {
        float r = acc / (den + 1e-16f) + ldf(bias2, 0, bf);
        if (bf) ((bf16*)out)[n] = __float2bfloat16(r);
        else    ((float*)out)[n] = r;
    }
}

// ---------------------------------------------------------------------------
extern "C" void kernel_launch(void* const* d_in, const int* in_sizes, int n_in,
                              void* d_out, int out_size, void* d_ws, size_t ws_size,
                              hipStream_t stream)
{
    const void* x        = d_in[0];
    const int*  ei       = (const int*)d_in[1];
    const void* W1       = d_in[2];
    const void* att_src1 = d_in[3];
    const void* att_dst1 = d_in[4];
    const void* b1       = d_in[5];
    const void* W2       = d_in[6];
    const void* att_src2 = d_in[7];
    const void* att_dst2 = d_in[8];
    const void* bias2    = d_in[9];

    int N = in_sizes[0] / 128;
    int E = in_sizes[1] / 2;

    char* ws = (char*)d_ws;
    size_t off = 0;
    auto alloc = [&](size_t bytes) -> void* {
        void* p = ws + off;
        off = (off + bytes + 255) & ~(size_t)255;
        return p;
    };
    int*   flags   = (int*)alloc(256);
    float* a_s     = (float*)alloc((size_t)N * 4 * sizeof(float));
    float* a_d     = (float*)alloc((size_t)N * 4 * sizeof(float));
    float* h2      = (float*)alloc((size_t)N * sizeof(float));
    int*   counts  = (int*)alloc((size_t)N * sizeof(int));
    int*   offsets = (int*)alloc((size_t)(N + 1) * sizeof(int));
    int*   cursor  = (int*)alloc((size_t)N * sizeof(int));
    int*   adj     = (int*)alloc((size_t)E * sizeof(int));
    int*   bsums   = (int*)alloc(4096);
    bf16*  h1b     = (bf16*)alloc((size_t)N * 128 * sizeof(bf16));

    k_detect<<<1, 256, 0, stream>>>(ei, (const unsigned*)x, flags);
    k_zero<<<(N + 255) / 256, 256, 0, stream>>>(counts, N);

    k_count<<<(E + 255) / 256, 256, 0, stream>>>(ei, flags, counts, E, N);
    int nb = (N + 511) / 512;
    k_bsum<<<nb, 512, 0, stream>>>(counts, bsums, N);
    k_scan_bsums<<<1, 512, 0, stream>>>(bsums, nb);
    k_offsets<<<nb, 512, 0, stream>>>(counts, bsums, offsets, cursor, N, E);
    k_scatter<<<(E + 255) / 256, 256, 0, stream>>>(ei, flags, cursor, adj, E, N);

    k_gemm1_mfma<<<(N + 63) / 64, 256, 0, stream>>>(x, W1, flags, h1b, N);
    k_asd<<<((size_t)N * 64 + 255) / 256, 256, 0, stream>>>(
        h1b, att_src1, att_dst1, flags, a_s, a_d, N);

    k_agg1<<<N, 128, 0, stream>>>(h1b, a_s, a_d, offsets, adj,
                                  b1, W2, flags, h2, N);

    k_agg2<<<((size_t)N * 16 + 255) / 256, 256, 0, stream>>>(
        h2, offsets, adj, att_src2, att_dst2, bias2, flags, d_out, N);
}

// Round 6
// 409.481 us; speedup vs baseline: 1.3413x; 1.3413x over previous
//
#include <hip/hip_runtime.h>
#include <hip/hip_bf16.h>
#include <math.h>

typedef __hip_bfloat16 bf16;
typedef __attribute__((ext_vector_type(8))) short short8v;
typedef __attribute__((ext_vector_type(4))) float float4v;

__device__ __forceinline__ float b2f(bf16 v) { return __bfloat162float(v); }
__device__ __forceinline__ float bs2f(unsigned short s) {
    unsigned u = ((unsigned)s) << 16;
    float f; __builtin_memcpy(&f, &u, 4); return f;
}
__device__ __forceinline__ short f2bs(float v) {
    bf16 b = __float2bfloat16(v);
    short s; __builtin_memcpy(&s, &b, 2); return s;
}
__device__ __forceinline__ float lrelu(float v) { return v > 0.f ? v : 0.2f * v; }
__device__ __forceinline__ float ldf(const void* p, size_t i, int bf) {
    return bf ? b2f(((const bf16*)p)[i]) : ((const float*)p)[i];
}
__device__ __forceinline__ int ld_src(const int* ei, int e, int E, int f64, int N) {
    int v = f64 ? (int)(((const long long*)ei)[e]) : ei[e];
    if ((unsigned)v >= (unsigned)N) v = 0;
    return v;
}
__device__ __forceinline__ int ld_dst(const int* ei, int e, int E, int f64, int N) {
    int v = f64 ? (int)(((const long long*)ei)[(size_t)E + e]) : ei[(size_t)E + e];
    if ((unsigned)v >= (unsigned)N) v = 0;
    return v;
}

#define EPB 4096   // edges per block in binning passes
#define SB  9      // bucket shift: 512 nodes per bucket

// ---------------------------------------------------------------------------
// K0: dtype detection. flags[0]=int64 edge index, flags[1]=bf16 floats.
// ---------------------------------------------------------------------------
__global__ void k_detect(const int* __restrict__ ei, const unsigned* __restrict__ xw,
                         int* __restrict__ flags)
{
    __shared__ int s_or[256];
    __shared__ int s_cnt[256];
    int t = threadIdx.x;
    int any = 0, cnt = 0;
    for (int i = t; i < 4096; i += 256) {
        any |= ei[2 * i + 1];
        unsigned e = (xw[i] >> 7) & 0xFFu;
        cnt += (e >= 100u && e <= 134u) ? 1 : 0;
    }
    s_or[t] = any; s_cnt[t] = cnt;
    __syncthreads();
    for (int s = 128; s > 0; s >>= 1) {
        if (t < s) { s_or[t] |= s_or[t + s]; s_cnt[t] += s_cnt[t + s]; }
        __syncthreads();
    }
    if (t == 0) {
        flags[0] = (s_or[0] == 0) ? 1 : 0;
        flags[1] = (s_cnt[0] > 2048) ? 1 : 0;
    }
}

__global__ void k_zero(int* __restrict__ p, int n)
{
    int i = blockIdx.x * blockDim.x + threadIdx.x;
    if (i < n) p[i] = 0;
}

// ---------------------------------------------------------------------------
// CSR build, bucket-local (no global random atomics).
// Pass 1: per-block LDS bucket histogram -> few global atomics.
// ---------------------------------------------------------------------------
__global__ void __launch_bounds__(256)
k_bbin_count(const int* __restrict__ ei, const int* __restrict__ flags,
             int* __restrict__ bcnt, int E, int N, int nbuck)
{
    __shared__ int hist[512];
    int t = threadIdx.x;
    for (int j = t; j < nbuck; j += 256) hist[j] = 0;
    __syncthreads();
    int f = flags[0];
    int beg = blockIdx.x * EPB, end = min(E, beg + EPB);
    for (int i = beg + t; i < end; i += 256)
        atomicAdd(&hist[ld_dst(ei, i, E, f, N) >> SB], 1);
    __syncthreads();
    for (int j = t; j < nbuck; j += 256)
        if (hist[j]) atomicAdd(&bcnt[j], hist[j]);
}

// scan bucket counts (nbuck <= 256): bofs = exclusive scan, bcur = copy
__global__ void k_bscan(const int* __restrict__ bcnt, int* __restrict__ bofs,
                        int* __restrict__ bcur, int* __restrict__ offsets,
                        int nbuck, int E, int N)
{
    __shared__ int sh[256];
    int t = threadIdx.x;
    int v = (t < nbuck) ? bcnt[t] : 0;
    sh[t] = v;
    __syncthreads();
    for (int s = 1; s < 256; s <<= 1) {
        int add = (t >= s) ? sh[t - s] : 0;
        __syncthreads();
        sh[t] += add;
        __syncthreads();
    }
    if (t < nbuck) { bofs[t] = sh[t] - v; bcur[t] = sh[t] - v; }
    if (t == 0) { bofs[nbuck] = E; offsets[N] = E; }
}

// Pass 2: blocks reserve contiguous per-bucket ranges, append (src,dst).
__global__ void __launch_bounds__(256)
k_bbin_scatter(const int* __restrict__ ei, const int* __restrict__ flags,
               int* __restrict__ bcur, uint2* __restrict__ ebuf,
               int E, int N, int nbuck)
{
    __shared__ int hist[512];
    __shared__ int base[512];
    int t = threadIdx.x;
    for (int j = t; j < nbuck; j += 256) hist[j] = 0;
    __syncthreads();
    int f = flags[0];
    int beg = blockIdx.x * EPB, end = min(E, beg + EPB);
    for (int i = beg + t; i < end; i += 256)
        atomicAdd(&hist[ld_dst(ei, i, E, f, N) >> SB], 1);
    __syncthreads();
    for (int j = t; j < nbuck; j += 256) {
        base[j] = hist[j] ? atomicAdd(&bcur[j], hist[j]) : 0;
        hist[j] = 0;  // reuse as local cursor
    }
    __syncthreads();
    for (int i = beg + t; i < end; i += 256) {
        int d = ld_dst(ei, i, E, f, N);
        int s = ld_src(ei, i, E, f, N);
        int b = d >> SB;
        int idx = base[b] + atomicAdd(&hist[b], 1);
        ebuf[idx] = make_uint2((unsigned)s, (unsigned)d);
    }
}

// Pass 3: one block per bucket. Node histogram + local scan -> CSR offsets,
// then scatter adj within the bucket's (L2-resident) range.
__global__ void __launch_bounds__(256)
k_bucket_csr(const uint2* __restrict__ ebuf, const int* __restrict__ bofs,
             int* __restrict__ offsets, int* __restrict__ adj, int N)
{
    const int npb = 1 << SB;          // 512 nodes per bucket
    __shared__ int hist[npb];
    __shared__ int psum[256];
    int b = blockIdx.x, t = threadIdx.x;
    int n0 = b << SB;
    int ebeg = bofs[b], eend = bofs[b + 1];

    hist[t] = 0; hist[t + 256] = 0;
    __syncthreads();
    for (int i = ebeg + t; i < eend; i += 256)
        atomicAdd(&hist[ebuf[i].y - n0], 1);
    __syncthreads();
    // scan: thread t owns hist[2t], hist[2t+1]
    int c0 = hist[2 * t], c1 = hist[2 * t + 1];
    int s = c0 + c1;
    psum[t] = s;
    __syncthreads();
    for (int st = 1; st < 256; st <<= 1) {
        int add = (t >= st) ? psum[t - st] : 0;
        __syncthreads();
        psum[t] += add;
        __syncthreads();
    }
    int run = ebeg + psum[t] - s;
    int node0 = n0 + 2 * t;
    hist[2 * t] = run;
    if (node0 < N) offsets[node0] = run;
    run += c0;
    hist[2 * t + 1] = run;
    if (node0 + 1 < N) offsets[node0 + 1] = run;
    __syncthreads();
    for (int i = ebeg + t; i < eend; i += 256) {
        uint2 e = ebuf[i];
        int pos = atomicAdd(&hist[e.y - n0], 1);
        adj[pos] = (int)e.x;
    }
}

// ---------------------------------------------------------------------------
// K1: h1 = x @ W1 via MFMA 16x16x32 bf16. Block = 256 thr (4 waves), 64 rows.
// ---------------------------------------------------------------------------
#define GP 136

__global__ void __launch_bounds__(256)
k_gemm1_mfma(const void* __restrict__ x, const void* __restrict__ W1,
             const int* __restrict__ flags, bf16* __restrict__ h1b, int N)
{
    __shared__ short w1t[128 * GP];
    __shared__ short xs[64 * GP];
    int bf = flags[1];
    int t = threadIdx.x;
    int m0 = blockIdx.x * 64;

    for (int idx = t; idx < 16384; idx += 256) {
        int k = idx >> 7, nn = idx & 127;
        w1t[nn * GP + k] = bf ? ((const short*)W1)[idx] : f2bs(((const float*)W1)[idx]);
    }
    for (int idx = t; idx < 8192; idx += 256) {
        int m = idx >> 7, k = idx & 127;
        int gm = m0 + m;
        float v = (gm < N) ? ldf(x, (size_t)gm * 128 + k, bf) : 0.f;
        xs[m * GP + k] = f2bs(v);
    }
    __syncthreads();

    int wv = t >> 6, l = t & 63, lq = l >> 4, lr = l & 15;

    short8v afr[4];
#pragma unroll
    for (int kk = 0; kk < 4; ++kk)
        afr[kk] = *(const short8v*)&xs[(wv * 16 + lr) * GP + kk * 32 + lq * 8];

    float4v acc[8];
#pragma unroll
    for (int ct = 0; ct < 8; ++ct) acc[ct] = (float4v){0.f, 0.f, 0.f, 0.f};

#pragma unroll
    for (int kk = 0; kk < 4; ++kk) {
        short8v a = afr[kk];
#pragma unroll
        for (int ct = 0; ct < 8; ++ct) {
            short8v bfr = *(const short8v*)&w1t[(ct * 16 + lr) * GP + kk * 32 + lq * 8];
            acc[ct] = __builtin_amdgcn_mfma_f32_16x16x32_bf16(a, bfr, acc[ct], 0, 0, 0);
        }
    }

#pragma unroll
    for (int ct = 0; ct < 8; ++ct) {
#pragma unroll
        for (int r = 0; r < 4; ++r) {
            int row = m0 + wv * 16 + lq * 4 + r;
            if (row < N)
                h1b[(size_t)row * 128 + ct * 16 + lr] = __float2bfloat16(acc[ct][r]);
        }
    }
}

// ---------------------------------------------------------------------------
// K2: a_s/a_d from h1b. One wave per node.
// ---------------------------------------------------------------------------
__global__ void k_asd(const bf16* __restrict__ h1b, const void* __restrict__ att_src,
                      const void* __restrict__ att_dst, const int* __restrict__ flags,
                      float* __restrict__ a_s, float* __restrict__ a_d, int N)
{
    int bf = flags[1];
    int gid = blockIdx.x * blockDim.x + threadIdx.x;
    int n = gid >> 6, l = gid & 63;
    if (n >= N) return;
    ushort2 u = *(const ushort2*)((const unsigned short*)h1b + (size_t)n * 128 + 2 * l);
    float v0 = bs2f(u.x), v1 = bs2f(u.y);
    float ps = v0 * ldf(att_src, 2 * l, bf) + v1 * ldf(att_src, 2 * l + 1, bf);
    float pd = v0 * ldf(att_dst, 2 * l, bf) + v1 * ldf(att_dst, 2 * l + 1, bf);
    for (int m = 1; m < 16; m <<= 1) {
        ps += __shfl_xor(ps, m, 64);
        pd += __shfl_xor(pd, m, 64);
    }
    if ((l & 15) == 0) {
        a_s[(size_t)n * 4 + (l >> 4)] = ps;
        a_d[(size_t)n * 4 + (l >> 4)] = pd;
    }
}

// ---------------------------------------------------------------------------
// K7: layer-1 softmax-aggregate (no max shift), fused +b1, ReLU, W2 proj.
// ---------------------------------------------------------------------------
__global__ void __launch_bounds__(128)
k_agg1(const bf16* __restrict__ h1b, const float* __restrict__ a_s,
       const float* __restrict__ a_d, const int* __restrict__ offsets,
       const int* __restrict__ adj, const void* __restrict__ b1,
       const void* __restrict__ W2, const int* __restrict__ flags,
       float* __restrict__ h2, int N)
{
    int bf = flags[1];
    int n = blockIdx.x, t = threadIdx.x;
    int w = t >> 6, l = t & 63, sub = l >> 5, j = l & 31;
    int hh = j >> 3;

    __shared__ float sad[4], sself[4], sden[4];
    __shared__ float swt[128 * 5];
    __shared__ int   sadj[128];
    __shared__ float facc[2][128];
    __shared__ float swred[2][4];
    __shared__ float w2sum[2];

    int beg = offsets[n], deg = offsets[n + 1] - beg;
    if (t < 4) {
        float adv = a_d[(size_t)n * 4 + t];
        sad[t] = adv;
        sself[t] = __expf(lrelu(a_s[(size_t)n * 4 + t] + adv));
    }
    __syncthreads();
    float ad0 = sad[0], ad1 = sad[1], ad2 = sad[2], ad3 = sad[3];

    float a0 = 0.f, a1 = 0.f, a2 = 0.f, a3 = 0.f;
    float dd0 = 0.f, dd1 = 0.f, dd2 = 0.f, dd3 = 0.f;
    const float4* as4 = (const float4*)a_s;
    const unsigned short* h1u = (const unsigned short*)h1b;

    for (int base = 0; base < deg; base += 128) {
        int chunk = min(128, deg - base);
        __syncthreads();
        if (t < chunk) {
            int s = adj[beg + base + t];
            sadj[t] = s;
            float4 av = as4[s];
            float w0 = __expf(lrelu(av.x + ad0));
            float w1 = __expf(lrelu(av.y + ad1));
            float w2v = __expf(lrelu(av.z + ad2));
            float w3 = __expf(lrelu(av.w + ad3));
            swt[t * 5 + 0] = w0; swt[t * 5 + 1] = w1;
            swt[t * 5 + 2] = w2v; swt[t * 5 + 3] = w3;
            dd0 += w0; dd1 += w1; dd2 += w2v; dd3 += w3;
        }
        __syncthreads();
        for (int k4 = 2 * w; k4 < chunk; k4 += 4) {
            int e = k4 + sub;
            if (e < chunk) {
                int s = sadj[e];
                float wt = swt[e * 5 + hh];
                ushort4 u = *(const ushort4*)(h1u + ((size_t)s << 7) + 4 * j);
                a0 += wt * bs2f(u.x);
                a1 += wt * bs2f(u.y);
                a2 += wt * bs2f(u.z);
                a3 += wt * bs2f(u.w);
            }
        }
    }
    for (int m = 1; m < 64; m <<= 1) {
        dd0 += __shfl_xor(dd0, m, 64);
        dd1 += __shfl_xor(dd1, m, 64);
        dd2 += __shfl_xor(dd2, m, 64);
        dd3 += __shfl_xor(dd3, m, 64);
    }
    if (l == 0) { swred[w][0] = dd0; swred[w][1] = dd1; swred[w][2] = dd2; swred[w][3] = dd3; }
    a0 += __shfl_xor(a0, 32, 64);
    a1 += __shfl_xor(a1, 32, 64);
    a2 += __shfl_xor(a2, 32, 64);
    a3 += __shfl_xor(a3, 32, 64);
    if (sub == 0) {
        facc[w][4 * j + 0] = a0; facc[w][4 * j + 1] = a1;
        facc[w][4 * j + 2] = a2; facc[w][4 * j + 3] = a3;
    }
    __syncthreads();
    if (t < 4) sden[t] = swred[0][t] + swred[1][t] + sself[t];
    __syncthreads();

    float selfv = sself[t >> 5] * b2f(h1b[((size_t)n << 7) + t]);
    float o = (facc[0][t] + facc[1][t] + selfv) / (sden[t >> 5] + 1e-16f) + ldf(b1, t, bf);
    o = fmaxf(o, 0.f);

    float p = o * ldf(W2, t, bf);
    for (int m = 1; m < 64; m <<= 1) p += __shfl_xor(p, m, 64);
    if (l == 0) w2sum[w] = p;
    __syncthreads();
    if (t == 0) h2[n] = w2sum[0] + w2sum[1];
}

// ---------------------------------------------------------------------------
// K8: layer-2 scalar softmax-aggregate, single pass. 16 lanes per node.
// ---------------------------------------------------------------------------
__global__ void k_agg2(const float* __restrict__ h2, const int* __restrict__ offsets,
                       const int* __restrict__ adj, const void* __restrict__ att_src2,
                       const void* __restrict__ att_dst2, const void* __restrict__ bias2,
                       const int* __restrict__ flags, void* __restrict__ out, int N)
{
    int bf = flags[1];
    int g = (blockIdx.x * blockDim.x + threadIdx.x) >> 4;
    int lane = threadIdx.x & 15;
    if (g >= N) return;
    int n = g;
    float as2 = ldf(att_src2, 0, bf), ad2 = ldf(att_dst2, 0, bf);
    int beg = offsets[n], end = offsets[n + 1], deg = end - beg;
    float hn = h2[n];
    float dterm = hn * ad2;

    float acc = 0.f, den = 0.f;
    if (lane == 0) {
        float ex = __expf(lrelu(hn * as2 + dterm));
        acc = ex * hn; den = ex;
    }
    for (int i = lane; i < deg; i += 16) {
        int s = adj[beg + i];
        float hs = h2[s];
        float ex = __expf(lrelu(hs * as2 + dterm));
        acc += ex * hs; den += ex;
    }
    for (int m = 1; m < 16; m <<= 1) {
        acc += __shfl_xor(acc, m, 64);
        den += __shfl_xor(den, m, 64);
    }
    if (lane == 0) {
        float r = acc / (den + 1e-16f) + ldf(bias2, 0, bf);
        if (bf) ((bf16*)out)[n] = __float2bfloat16(r);
        else    ((float*)out)[n] = r;
    }
}

// ---------------------------------------------------------------------------
extern "C" void kernel_launch(void* const* d_in, const int* in_sizes, int n_in,
                              void* d_out, int out_size, void* d_ws, size_t ws_size,
                              hipStream_t stream)
{
    const void* x        = d_in[0];
    const int*  ei       = (const int*)d_in[1];
    const void* W1       = d_in[2];
    const void* att_src1 = d_in[3];
    const void* att_dst1 = d_in[4];
    const void* b1       = d_in[5];
    const void* W2       = d_in[6];
    const void* att_src2 = d_in[7];
    const void* att_dst2 = d_in[8];
    const void* bias2    = d_in[9];

    int N = in_sizes[0] / 128;
    int E = in_sizes[1] / 2;
    int nbuck = ((N - 1) >> SB) + 1;   // 196 for N=100k (must be <= 256)

    char* ws = (char*)d_ws;
    size_t off = 0;
    auto alloc = [&](size_t bytes) -> void* {
        void* p = ws + off;
        off = (off + bytes + 255) & ~(size_t)255;
        return p;
    };
    int*   flags   = (int*)alloc(256);
    float* a_s     = (float*)alloc((size_t)N * 4 * sizeof(float));
    float* a_d     = (float*)alloc((size_t)N * 4 * sizeof(float));
    float* h2      = (float*)alloc((size_t)N * sizeof(float));
    int*   offsets = (int*)alloc((size_t)(N + 1) * sizeof(int));
    int*   adj     = (int*)alloc((size_t)E * sizeof(int));
    uint2* ebuf    = (uint2*)alloc((size_t)E * sizeof(uint2));
    int*   bcnt    = (int*)alloc(512 * sizeof(int));
    int*   bofs    = (int*)alloc(516 * sizeof(int));
    int*   bcur    = (int*)alloc(512 * sizeof(int));
    bf16*  h1b     = (bf16*)alloc((size_t)N * 128 * sizeof(bf16));

    k_detect<<<1, 256, 0, stream>>>(ei, (const unsigned*)x, flags);
    k_zero<<<(nbuck + 255) / 256, 256, 0, stream>>>(bcnt, nbuck);

    int ebl = (E + EPB - 1) / EPB;
    k_bbin_count<<<ebl, 256, 0, stream>>>(ei, flags, bcnt, E, N, nbuck);
    k_bscan<<<1, 256, 0, stream>>>(bcnt, bofs, bcur, offsets, nbuck, E, N);
    k_bbin_scatter<<<ebl, 256, 0, stream>>>(ei, flags, bcur, ebuf, E, N, nbuck);
    k_bucket_csr<<<nbuck, 256, 0, stream>>>(ebuf, bofs, offsets, adj, N);

    k_gemm1_mfma<<<(N + 63) / 64, 256, 0, stream>>>(x, W1, flags, h1b, N);
    k_asd<<<((size_t)N * 64 + 255) / 256, 256, 0, stream>>>(
        h1b, att_src1, att_dst1, flags, a_s, a_d, N);

    k_agg1<<<N, 128, 0, stream>>>(h1b, a_s, a_d, offsets, adj,
                                  b1, W2, flags, h2, N);

    k_agg2<<<((size_t)N * 16 + 255) / 256, 256, 0, stream>>>(
        h2, offsets, adj, att_src2, att_dst2, bias2, flags, d_out, N);
}